// Round 1
// baseline (360.750 us; speedup 1.0000x reference)
//
#include <hip/hip_runtime.h>

// Trilinear resize [4,128,128,128,2] f32 -> [4,192,192,192,2] f32.
// One thread = 2 output voxels (x, x+1) * 2 channels = one float4 store.

#define IN_D   128
#define OUT_D  192
#define OUT_XP 96   // OUT_D / 2 (pairs of x)

__device__ __forceinline__ void axis_weights(int o, int& i0, int& i1,
                                             float& w0, float& w1) {
    // Mirrors reference: loc = o / zoom (fp32 divide), zoom = 1.5
    float loc = (float)o / 1.5f;
    float fl  = floorf(loc);
    int a = (int)fl;
    if (a > IN_D - 1) a = IN_D - 1;      // clip (loc >= 0 always)
    int b = a + 1;
    if (b > IN_D - 1) b = IN_D - 1;
    float cloc = fminf(loc, (float)(IN_D - 1));
    i0 = a; i1 = b;
    w0 = (float)b - cloc;                // weight for corner 0
    w1 = 1.0f - w0;
}

__global__ __launch_bounds__(256) void resize_trilinear_kernel(
        const float2* __restrict__ in, float4* __restrict__ out, int total) {
    int idx = blockIdx.x * blockDim.x + threadIdx.x;
    if (idx >= total) return;

    // idx -> (b, z, y, x-pair); x fastest for coalesced stores
    int xp = idx % OUT_XP;
    int t  = idx / OUT_XP;
    int y  = t % OUT_D;
    t /= OUT_D;
    int z  = t % OUT_D;
    int b  = t / OUT_D;

    int y0, y1, z0, z1;
    float wy0, wy1, wz0, wz1;
    axis_weights(y, y0, y1, wy0, wy1);
    axis_weights(z, z0, z1, wz0, wz1);

    const float2* base = in + (size_t)b * (IN_D * IN_D * IN_D);
    const float2* r00 = base + (z0 * IN_D + y0) * IN_D;  // z0,y0 row
    const float2* r01 = base + (z0 * IN_D + y1) * IN_D;  // z0,y1
    const float2* r10 = base + (z1 * IN_D + y0) * IN_D;  // z1,y0
    const float2* r11 = base + (z1 * IN_D + y1) * IN_D;  // z1,y1

    float2 res[2];
#pragma unroll
    for (int k = 0; k < 2; ++k) {
        int x = 2 * xp + k;
        int x0, x1;
        float wx0, wx1;
        axis_weights(x, x0, x1, wx0, wx1);

        float2 a00 = r00[x0], b00 = r00[x1];
        float2 a01 = r01[x0], b01 = r01[x1];
        float2 a10 = r10[x0], b10 = r10[x1];
        float2 a11 = r11[x0], b11 = r11[x1];

        // lerp along x (per channel)
        float v00x = a00.x * wx0 + b00.x * wx1;
        float v00y = a00.y * wx0 + b00.y * wx1;
        float v01x = a01.x * wx0 + b01.x * wx1;
        float v01y = a01.y * wx0 + b01.y * wx1;
        float v10x = a10.x * wx0 + b10.x * wx1;
        float v10y = a10.y * wx0 + b10.y * wx1;
        float v11x = a11.x * wx0 + b11.x * wx1;
        float v11y = a11.y * wx0 + b11.y * wx1;

        // lerp along y
        float v0x = v00x * wy0 + v01x * wy1;
        float v0y = v00y * wy0 + v01y * wy1;
        float v1x = v10x * wy0 + v11x * wy1;
        float v1y = v10y * wy0 + v11y * wy1;

        // lerp along z
        res[k].x = v0x * wz0 + v1x * wz1;
        res[k].y = v0y * wz0 + v1y * wz1;
    }

    out[idx] = make_float4(res[0].x, res[0].y, res[1].x, res[1].y);
}

extern "C" void kernel_launch(void* const* d_in, const int* in_sizes, int n_in,
                              void* d_out, int out_size, void* d_ws, size_t ws_size,
                              hipStream_t stream) {
    const float2* in = (const float2*)d_in[0];
    float4* out = (float4*)d_out;

    // total float4 outputs = 4 * 192 * 192 * 96 = 14,155,776
    int total = 4 * OUT_D * OUT_D * OUT_XP;
    int block = 256;
    int grid = (total + block - 1) / block;  // 55,296 blocks exactly

    resize_trilinear_kernel<<<grid, block, 0, stream>>>(in, out, total);
}

// Round 2
// 300.951 us; speedup vs baseline: 1.1987x; 1.1987x over previous
//
#include <hip/hip_runtime.h>

// Trilinear resize [4,128,128,128,2] f32 -> [4,192,192,192,2] f32.
// zoom = 1.5 exactly => weights are periodic with period 3 outputs / 2 inputs:
//   for output o: m = o/3, r = o%3; i0 = 2m + (r==2); i1 = min(i0+1,127);
//   w0 = {1, 1/3, 2/3}[r]; w1 = 1-w0.
// (When clipped i0==i1 the w split is irrelevant since w0+w1=1.)
// One thread: 1 x-pair (2 outputs * 2ch = float4) for 3 consecutive z outputs,
// fed by 3 input z-planes * 2 y-rows * 3 x-positions = 18 float2 loads
// -> 3 coalesced float4 stores.

#define IN_D  128
#define OUT_D 192
#define OUT_XP 96

__global__ __launch_bounds__(192) void resize_trilinear_kernel(
        const float2* __restrict__ in, float4* __restrict__ out) {
    const int xp = (int)threadIdx.x;                    // 0..95
    const int y  = (int)(blockIdx.x * 2 + threadIdx.y); // 0..191
    const int zt = (int)blockIdx.y;                     // 0..63 (z-triple)
    const int b  = (int)blockIdx.z;                     // 0..3

    const float THIRD = 0.33333334f;
    const float TWO3  = 0.66666669f;

    // ---- x pair (x = 2*xp, 2*xp+1) ----
    unsigned xo = 2u * (unsigned)xp;
    unsigned mx = xo / 3u;               // compiler emits magic-mul
    unsigned rx = xo - 3u * mx;
    int xbase = 2 * (int)mx + (rx == 2u ? 1 : 0);
    int xi1 = min(xbase + 1, IN_D - 1);
    int xi2 = min(xbase + 2, IN_D - 1);
    // k0 (x=2xp): corners (V0,V1), w0 = lut[rx]
    float wxa0 = (rx == 0u) ? 1.0f : ((rx == 1u) ? THIRD : TWO3);
    float wxa1 = 1.0f - wxa0;
    // k1 (x=2xp+1): r' = (rx+1)%3; corners (V0,V1) if rx==0 else (V1,V2)
    float wxb0 = (rx == 0u) ? THIRD : ((rx == 1u) ? TWO3 : 1.0f);
    float wxb1 = 1.0f - wxb0;
    bool sel = (rx != 0u);

    // ---- y ----
    unsigned uy = (unsigned)y;
    unsigned my = uy / 3u;
    unsigned ry = uy - 3u * my;
    int y0 = 2 * (int)my + (ry == 2u ? 1 : 0);
    int y1 = min(y0 + 1, IN_D - 1);
    float wy0 = (ry == 0u) ? 1.0f : ((ry == 1u) ? THIRD : TWO3);
    float wy1 = 1.0f - wy0;

    // ---- z planes for outputs 3zt, 3zt+1, 3zt+2 ----
    int pz0 = 2 * zt;
    int pz1 = 2 * zt + 1;
    int pz2 = min(2 * zt + 2, IN_D - 1);

    const float2* basep = in + (size_t)b * (IN_D * IN_D * IN_D);

    float2 u0[3], u1[3];  // x-pair results per input z-plane
#pragma unroll
    for (int p = 0; p < 3; ++p) {
        int pz = (p == 0) ? pz0 : ((p == 1) ? pz1 : pz2);
        const float2* rA = basep + (size_t)(pz * IN_D + y0) * IN_D;
        const float2* rB = basep + (size_t)(pz * IN_D + y1) * IN_D;
        float2 a0 = rA[xbase], a1 = rA[xi1], a2 = rA[xi2];
        float2 b0 = rB[xbase], b1 = rB[xi1], b2 = rB[xi2];
        // y-lerp at the 3 x positions
        float2 V0, V1, V2;
        V0.x = a0.x * wy0 + b0.x * wy1;  V0.y = a0.y * wy0 + b0.y * wy1;
        V1.x = a1.x * wy0 + b1.x * wy1;  V1.y = a1.y * wy0 + b1.y * wy1;
        V2.x = a2.x * wy0 + b2.x * wy1;  V2.y = a2.y * wy0 + b2.y * wy1;
        // x-lerp for the two outputs of the pair
        u0[p].x = V0.x * wxa0 + V1.x * wxa1;
        u0[p].y = V0.y * wxa0 + V1.y * wxa1;
        float2 c0 = sel ? V1 : V0;
        float2 c1 = sel ? V2 : V1;
        u1[p].x = c0.x * wxb0 + c1.x * wxb1;
        u1[p].y = c0.y * wxb0 + c1.y * wxb1;
    }

    // ---- z combine: out z=3zt -> plane0; 3zt+1 -> p0/3+2p1/3; 3zt+2 -> 2p1/3+p2/3
    float4 o0, o1, o2;
    o0.x = u0[0].x;  o0.y = u0[0].y;  o0.z = u1[0].x;  o0.w = u1[0].y;
    o1.x = u0[0].x * THIRD + u0[1].x * TWO3;
    o1.y = u0[0].y * THIRD + u0[1].y * TWO3;
    o1.z = u1[0].x * THIRD + u1[1].x * TWO3;
    o1.w = u1[0].y * THIRD + u1[1].y * TWO3;
    o2.x = u0[1].x * TWO3 + u0[2].x * THIRD;
    o2.y = u0[1].y * TWO3 + u0[2].y * THIRD;
    o2.z = u1[1].x * TWO3 + u1[2].x * THIRD;
    o2.w = u1[1].y * TWO3 + u1[2].y * THIRD;

    size_t ob = (((size_t)b * OUT_D + 3 * zt) * OUT_D + y) * OUT_XP + xp;
    const size_t zs = (size_t)OUT_D * OUT_XP;
    out[ob]          = o0;
    out[ob + zs]     = o1;
    out[ob + 2 * zs] = o2;
}

extern "C" void kernel_launch(void* const* d_in, const int* in_sizes, int n_in,
                              void* d_out, int out_size, void* d_ws, size_t ws_size,
                              hipStream_t stream) {
    const float2* in = (const float2*)d_in[0];
    float4* out = (float4*)d_out;

    dim3 block(OUT_XP, 2, 1);   // 192 threads = 3 waves
    dim3 grid(OUT_D / 2, 64, 4); // y-pairs, z-triples, batch

    resize_trilinear_kernel<<<grid, block, 0, stream>>>(in, out);
}